// Round 2
// baseline (22010.098 us; speedup 1.0000x reference)
//
#include <hip/hip_runtime.h>

// Teacher-forced GRU + additive attention decoder, MI355X. FLOAT32 I/O.
// B=32 independent recurrences -> 8 blocks per batch elem, flag-synced, persistent.
#define BB    32
#define TDEC  400
#define TENC  800
#define EDIM  256
#define GDIM  256
#define ADIM  128
#define IDIM  80
#define G3    768
#define NSL   8     // slices (blocks) per batch element
#define SLH   32    // GDIM/NSL h-elements per slice
#define SLT   100   // TENC/NSL encoder timesteps per slice

typedef unsigned short u16;
typedef unsigned int u32;

__device__ __forceinline__ float b2f(u16 u) {
  union { u32 i; float f; } x; x.i = ((u32)u) << 16; return x.f;
}
__device__ __forceinline__ u16 f2b(float f) {
  union { float f; u32 u; } x; x.f = f;
  u32 u = x.u; u += 0x7fffu + ((u >> 16) & 1u);
  return (u16)(u >> 16);
}
// 8 bf16 -> 8 f32 (16B load)
__device__ __forceinline__ void ld8(const u16* p, float* w) {
  const uint4 q = *reinterpret_cast<const uint4*>(p);
  union { u32 i; float f; } c;
  c.i = q.x << 16;          w[0] = c.f;
  c.i = q.x & 0xffff0000u;  w[1] = c.f;
  c.i = q.y << 16;          w[2] = c.f;
  c.i = q.y & 0xffff0000u;  w[3] = c.f;
  c.i = q.z << 16;          w[4] = c.f;
  c.i = q.z & 0xffff0000u;  w[5] = c.f;
  c.i = q.w << 16;          w[6] = c.f;
  c.i = q.w & 0xffff0000u;  w[7] = c.f;
}
// 8 f32 (two 16B loads)
__device__ __forceinline__ void ldf8(const float* p, float* w) {
  const float4 a = *reinterpret_cast<const float4*>(p);
  const float4 b = *reinterpret_cast<const float4*>(p + 4);
  w[0] = a.x; w[1] = a.y; w[2] = a.z; w[3] = a.w;
  w[4] = b.x; w[5] = b.y; w[6] = b.z; w[7] = b.w;
}
__device__ __forceinline__ float fsigmoid(float x) {
  return __builtin_amdgcn_rcpf(1.f + __expf(-x));
}
__device__ __forceinline__ float ftanh(float x) {
  float e = __expf(2.f * x);
  return 1.f - 2.f * __builtin_amdgcn_rcpf(e + 1.f);
}

// ---------------- K1: gi_x[b][t][g] = x_t . W_ih[:, :80] + b_ih (bf16 out) -----
__global__ __launch_bounds__(256) void k_gix(
    const float* __restrict__ gt, const float* __restrict__ W_ih,
    const float* __restrict__ b_ih, u16* __restrict__ gi_x) {
  __shared__ float sc_x[8][IDIM];
  const int tid = threadIdx.x;
  const int b = blockIdx.x / 50;
  const int t0 = (blockIdx.x % 50) * 8;
  for (int idx = tid; idx < 8 * IDIM; idx += 256) {
    int row = idx / IDIM, col = idx % IDIM;
    sc_x[row][col] = gt[((size_t)b * TDEC + t0 + row) * IDIM + col];
  }
  __syncthreads();
  for (int kk = 0; kk < 3; ++kk) {
    const int g = tid + 256 * kk;
    const float* wrow = W_ih + (size_t)g * 336;
    float acc[8] = {0,0,0,0,0,0,0,0};
    #pragma unroll 2
    for (int k8 = 0; k8 < IDIM / 8; ++k8) {
      float w[8]; ldf8(wrow + (k8 << 3), w);
      #pragma unroll
      for (int tt = 0; tt < 8; ++tt) {
        const float* x = &sc_x[tt][k8 << 3];
        acc[tt] += w[0]*x[0] + w[1]*x[1] + w[2]*x[2] + w[3]*x[3]
                 + w[4]*x[4] + w[5]*x[5] + w[6]*x[6] + w[7]*x[7];
      }
    }
    const float bias = b_ih[g];
    #pragma unroll
    for (int tt = 0; tt < 8; ++tt)
      gi_x[((size_t)b * TDEC + t0 + tt) * G3 + g] = f2b(acc[tt] + bias);
  }
}

// ---------------- K2: enc_proj[b][te][a] = enc_feat . W_enc^T (bf16 out) -------
__global__ __launch_bounds__(256) void k_encp(
    const float* __restrict__ enc_feat, const float* __restrict__ W_enc,
    u16* __restrict__ encp) {
  __shared__ float sc_x[16][EDIM];
  const int tid = threadIdx.x;
  const int b = blockIdx.x / 50;
  const int te0 = (blockIdx.x % 50) * 16;
  for (int idx = tid; idx < 16 * EDIM; idx += 256) {
    int row = idx >> 8, col = idx & 255;
    sc_x[row][col] = enc_feat[((size_t)b * TENC + te0 + row) * EDIM + col];
  }
  __syncthreads();
  const int a = tid & 127;
  const int tg = tid >> 7;
  const float* wrow = W_enc + (size_t)a * EDIM;
  float acc[8] = {0,0,0,0,0,0,0,0};
  #pragma unroll 4
  for (int k8 = 0; k8 < EDIM / 8; ++k8) {
    float w[8]; ldf8(wrow + (k8 << 3), w);
    #pragma unroll
    for (int tt = 0; tt < 8; ++tt) {
      const float* x = &sc_x[tg * 8 + tt][k8 << 3];
      acc[tt] += w[0]*x[0] + w[1]*x[1] + w[2]*x[2] + w[3]*x[3]
               + w[4]*x[4] + w[5]*x[5] + w[6]*x[6] + w[7]*x[7];
    }
  }
  #pragma unroll
  for (int tt = 0; tt < 8; ++tt)
    encp[((size_t)b * TENC + te0 + tg * 8 + tt) * ADIM + a] = f2b(acc[tt]);
}

// ---------------- K3: persistent step loop (8 blocks per batch elem) -----------
__global__ __launch_bounds__(256) void k_decode(
    const float* __restrict__ enc_feat, const float* __restrict__ W_ih,
    const float* __restrict__ W_hh, const float* __restrict__ b_hh,
    const float* __restrict__ W_dec, const float* __restrict__ b_attn,
    const float* __restrict__ v_attn, const u16* __restrict__ gi_x,
    const u16* __restrict__ encp, float* __restrict__ stash,
    float* __restrict__ Xh, float* __restrict__ Xdec,
    float* __restrict__ Xctx, float* __restrict__ Xsum,
    int* __restrict__ flagA, int* __restrict__ flagB,
    float* __restrict__ out_attn) {
  __shared__ float sc_in[512];       // [0..256)=ctx(t-1), [256..512)=h(t-1)
  __shared__ float sc_dec[ADIM];
  __shared__ float sc_g0[96];
  __shared__ float sc_g1[96];
  __shared__ float sc_hnl[SLH];
  __shared__ float sc_w[SLT];
  __shared__ float sc_v[ADIM];

  const int tid = threadIdx.x;
  const int b = blockIdx.x & 31;
  const int j = blockIdx.x >> 5;

  if (tid < ADIM) sc_v[tid] = v_attn[tid];
  sc_in[tid] = 0.f;
  sc_in[256 + tid] = 0.f;
  __syncthreads();

  for (int t = 0; t < TDEC; ++t) {
    // -------- phase 1: gate dots (this block's 32 h-elems: rows 32j..32j+32) ---
    if (tid < 192) {
      const int r = tid >> 1;           // local gate row 0..96 (r|z|n x 32)
      const int part = tid & 1;         // 0: ctx . W_ih-cols, 1: h . W_hh
      const int grow = ((r >> 5) << 8) + SLH * j + (r & 31);
      const float* wrow = part ? (W_hh + (size_t)grow * GDIM)
                               : (W_ih + (size_t)grow * 336 + 80);
      const float* act = sc_in + (part << 8);
      const float tail = part ? b_hh[grow]
                              : b2f(gi_x[((size_t)b * TDEC + t) * G3 + grow]);
      float acc = 0.f;
      #pragma unroll 8
      for (int k8 = 0; k8 < EDIM / 8; ++k8) {
        float w[8]; ldf8(wrow + (k8 << 3), w);
        const float* a8 = act + (k8 << 3);
        acc += w[0]*a8[0] + w[1]*a8[1] + w[2]*a8[2] + w[3]*a8[3]
             + w[4]*a8[4] + w[5]*a8[5] + w[6]*a8[6] + w[7]*a8[7];
      }
      (part ? sc_g1 : sc_g0)[r] = acc + tail;
    }
    __syncthreads();
    if (tid < SLH) {  // GRU pointwise
      const float gr = sc_g0[tid] + sc_g1[tid];
      const float gz = sc_g0[SLH + tid] + sc_g1[SLH + tid];
      const float rr = fsigmoid(gr);
      const float zz = fsigmoid(gz);
      const float nn = ftanh(sc_g0[2 * SLH + tid] + rr * sc_g1[2 * SLH + tid]);
      const float hp = sc_in[256 + SLH * j + tid];
      const float hn = (1.f - zz) * nn + zz * hp;
      sc_hnl[tid] = hn;
      Xh[b * GDIM + SLH * j + tid] = hn;
      stash[((size_t)b * TDEC + t) * 512 + SLH * j + tid] = hn;
    }
    __syncthreads();
    if (tid < ADIM) {  // dec_proj partial from this block's h slice
      const float* wrow = W_dec + (size_t)tid * GDIM + SLH * j;
      float acc = 0.f;
      #pragma unroll
      for (int k8 = 0; k8 < SLH / 8; ++k8) {
        float w[8]; ldf8(wrow + (k8 << 3), w);
        const float* a8 = sc_hnl + (k8 << 3);
        acc += w[0]*a8[0] + w[1]*a8[1] + w[2]*a8[2] + w[3]*a8[3]
             + w[4]*a8[4] + w[5]*a8[5] + w[6]*a8[6] + w[7]*a8[7];
      }
      Xdec[(b * NSL + j) * ADIM + tid] = acc;
    }
    __syncthreads();
    __builtin_amdgcn_fence(__ATOMIC_RELEASE, "agent");
    if (tid == 0)
      __hip_atomic_store(&flagA[b * NSL + j], t + 1, __ATOMIC_RELEASE,
                         __HIP_MEMORY_SCOPE_AGENT);
    // -------- wait A: full h_new + dec partials ------------------------------
    if (tid < NSL)
      while (__hip_atomic_load(&flagA[b * NSL + tid], __ATOMIC_RELAXED,
                               __HIP_MEMORY_SCOPE_AGENT) < t + 1) {}
    __syncthreads();
    __builtin_amdgcn_fence(__ATOMIC_ACQUIRE, "agent");
    sc_in[256 + tid] = Xh[b * GDIM + tid];  // h(t) for next step
    if (tid < ADIM) {
      float d = b_attn[tid];
      #pragma unroll
      for (int jj = 0; jj < NSL; ++jj) d += Xdec[(b * NSL + jj) * ADIM + tid];
      sc_dec[tid] = d;
    }
    __syncthreads();
    // -------- phase 2a: scores for this block's 100 encoder steps ------------
    if (tid < 2 * SLT) {
      const int te = tid >> 1, half = tid & 1;
      const u16* ep = encp + ((size_t)b * TENC + SLT * j + te) * ADIM + 64 * half;
      const float* dptr = sc_dec + 64 * half;
      const float* vptr = sc_v + 64 * half;
      float s = 0.f;
      #pragma unroll 2
      for (int k8 = 0; k8 < 8; ++k8) {
        float w[8]; ld8(ep + (k8 << 3), w);
        #pragma unroll
        for (int i = 0; i < 8; ++i) {
          const int a = (k8 << 3) + i;
          s += ftanh(w[i] + dptr[a]) * vptr[a];
        }
      }
      s += __shfl_xor(s, 1);
      if (half == 0) sc_w[te] = __expf(s);  // |s| <= ||v||_1 ~ 5: max-free safe
    }
    __syncthreads();
    if (tid < 64) {  // partial exp-sum
      float v = sc_w[tid] + ((tid < SLT - 64) ? sc_w[tid + 64] : 0.f);
      #pragma unroll
      for (int off = 1; off < 64; off <<= 1) v += __shfl_xor(v, off);
      if (tid == 0) Xsum[b * NSL + j] = v;
    }
    {  // phase 2b: unnormalized ctx partial over this block's slice
      const float* ef = enc_feat + ((size_t)b * TENC + SLT * j) * EDIM + tid;
      float pc = 0.f;
      #pragma unroll 4
      for (int te = 0; te < SLT; ++te)
        pc += sc_w[te] * ef[(size_t)te * EDIM];
      Xctx[(b * NSL + j) * EDIM + tid] = pc;
    }
    __syncthreads();
    __builtin_amdgcn_fence(__ATOMIC_RELEASE, "agent");
    if (tid == 0)
      __hip_atomic_store(&flagB[b * NSL + j], t + 1, __ATOMIC_RELEASE,
                         __HIP_MEMORY_SCOPE_AGENT);
    // -------- wait B: combine ctx + write attn -------------------------------
    if (tid < NSL)
      while (__hip_atomic_load(&flagB[b * NSL + tid], __ATOMIC_RELAXED,
                               __HIP_MEMORY_SCOPE_AGENT) < t + 1) {}
    __syncthreads();
    __builtin_amdgcn_fence(__ATOMIC_ACQUIRE, "agent");
    {
      float S = 0.f;
      #pragma unroll
      for (int jj = 0; jj < NSL; ++jj) S += Xsum[b * NSL + jj];
      float c = 0.f;
      #pragma unroll
      for (int jj = 0; jj < NSL; ++jj) c += Xctx[(b * NSL + jj) * EDIM + tid];
      const float invS = __builtin_amdgcn_rcpf(S);
      const float cv = c * invS;
      sc_in[tid] = cv;  // ctx(t) for next step
      if (j == 0) stash[((size_t)b * TDEC + t) * 512 + EDIM + tid] = cv;
      if (tid < SLT)
        out_attn[((size_t)b * TDEC + t) * TENC + SLT * j + tid] =
            sc_w[tid] * invS;
    }
    __syncthreads();
  }
}

// ---------------- K4: pred = log_softmax([h;ctx] . W_out^T + b_out) ------------
__global__ __launch_bounds__(256) void k_pred(
    const float* __restrict__ stash, const float* __restrict__ W_out,
    const float* __restrict__ b_out, float* __restrict__ out_pred) {
  __shared__ float sc_s[4][512];
  __shared__ float sc_lp[2][4][IDIM];
  __shared__ float sc_l[4][IDIM];
  __shared__ float sc_lse[4];
  const int tid = threadIdx.x;
  const int b = blockIdx.x / 100;
  const int t0 = (blockIdx.x % 100) * 4;
  for (int idx = tid; idx < 4 * 512; idx += 256)
    sc_s[idx >> 9][idx & 511] = stash[((size_t)b * TDEC + t0) * 512 + idx];
  __syncthreads();
  const int o = tid & 127, kh = tid >> 7;
  if (o < IDIM) {
    const float* wrow = W_out + (size_t)o * 512 + kh * 256;
    float acc[4] = {0,0,0,0};
    #pragma unroll 4
    for (int k8 = 0; k8 < 32; ++k8) {
      float w[8]; ldf8(wrow + (k8 << 3), w);
      #pragma unroll
      for (int tt = 0; tt < 4; ++tt) {
        const float* x = &sc_s[tt][kh * 256 + (k8 << 3)];
        acc[tt] += w[0]*x[0] + w[1]*x[1] + w[2]*x[2] + w[3]*x[3]
                 + w[4]*x[4] + w[5]*x[5] + w[6]*x[6] + w[7]*x[7];
      }
    }
    #pragma unroll
    for (int tt = 0; tt < 4; ++tt) sc_lp[kh][tt][o] = acc[tt];
  }
  __syncthreads();
  if (tid < IDIM) {
    const float bb = b_out[tid];
    #pragma unroll
    for (int tt = 0; tt < 4; ++tt)
      sc_l[tt][tid] = sc_lp[0][tt][tid] + sc_lp[1][tt][tid] + bb;
  }
  __syncthreads();
  {
    const int w = tid >> 6, lane = tid & 63;
    const float a0 = sc_l[w][lane];
    const float a1 = (lane < IDIM - 64) ? sc_l[w][lane + 64] : -1e30f;
    float m = fmaxf(a0, a1);
    #pragma unroll
    for (int off = 1; off < 64; off <<= 1) m = fmaxf(m, __shfl_xor(m, off));
    float e = __expf(a0 - m) + ((lane < IDIM - 64) ? __expf(a1 - m) : 0.f);
    #pragma unroll
    for (int off = 1; off < 64; off <<= 1) e += __shfl_xor(e, off);
    if (lane == 0) sc_lse[w] = m + __logf(e);
  }
  __syncthreads();
  for (int idx = tid; idx < 4 * IDIM; idx += 256) {
    const int tt = idx / IDIM, oo = idx % IDIM;
    out_pred[((size_t)b * TDEC + t0 + tt) * IDIM + oo] =
        sc_l[tt][oo] - sc_lse[tt];
  }
}

extern "C" void kernel_launch(void* const* d_in, const int* in_sizes, int n_in,
                              void* d_out, int out_size, void* d_ws, size_t ws_size,
                              hipStream_t stream) {
  const float* enc_feat = (const float*)d_in[0];
  const float* gt       = (const float*)d_in[1];
  const float* W_ih     = (const float*)d_in[2];
  const float* W_hh     = (const float*)d_in[3];
  const float* b_ih     = (const float*)d_in[4];
  const float* b_hh     = (const float*)d_in[5];
  const float* W_enc    = (const float*)d_in[6];
  const float* W_dec    = (const float*)d_in[7];
  const float* b_attn   = (const float*)d_in[8];
  const float* v_attn   = (const float*)d_in[9];
  const float* W_out    = (const float*)d_in[10];
  const float* b_out    = (const float*)d_in[11];
  float* out_pred = (float*)d_out;
  float* out_attn = out_pred + (size_t)BB * TDEC * IDIM;

  char* ws = (char*)d_ws;
  size_t off = 0;
  u16* gi_x   = (u16*)(ws + off);   off += (size_t)BB * TDEC * G3 * 2;
  u16* encp   = (u16*)(ws + off);   off += (size_t)BB * TENC * ADIM * 2;
  float* stash= (float*)(ws + off); off += (size_t)BB * TDEC * 512 * 4;
  float* Xh   = (float*)(ws + off); off += (size_t)BB * GDIM * 4;
  float* Xdec = (float*)(ws + off); off += (size_t)BB * NSL * ADIM * 4;
  float* Xctx = (float*)(ws + off); off += (size_t)BB * NSL * EDIM * 4;
  float* Xsum = (float*)(ws + off); off += (size_t)BB * NSL * 4;
  int* flagA  = (int*)(ws + off);   off += (size_t)BB * NSL * 4;
  int* flagB  = (int*)(ws + off);   off += (size_t)BB * NSL * 4;

  hipMemsetAsync(flagA, 0, (size_t)BB * NSL * 4 * 2, stream);  // zero A+B

  hipLaunchKernelGGL(k_gix, dim3(BB * 50), dim3(256), 0, stream,
                     gt, W_ih, b_ih, gi_x);
  hipLaunchKernelGGL(k_encp, dim3(BB * 50), dim3(256), 0, stream,
                     enc_feat, W_enc, encp);
  hipLaunchKernelGGL(k_decode, dim3(BB * NSL), dim3(256), 0, stream,
                     enc_feat, W_ih, W_hh, b_hh, W_dec, b_attn, v_attn,
                     gi_x, encp, stash, Xh, Xdec, Xctx, Xsum,
                     flagA, flagB, out_attn);
  hipLaunchKernelGGL(k_pred, dim3(BB * 100), dim3(256), 0, stream,
                     stash, W_out, b_out, out_pred);
}

// Round 3
// 5067.308 us; speedup vs baseline: 4.3435x; 4.3435x over previous
//
#include <hip/hip_runtime.h>

// Teacher-forced GRU + additive attention decoder, MI355X. FLOAT32 I/O.
// Round 3: fence-free cross-block protocol (relaxed agent atomics through LLC,
// NO L2-invalidating acquire fences), gate weights staged in LDS as bf16,
// NSL=16 blocks per batch element (512 blocks, 2/CU).
#define BB    32
#define TDEC  400
#define TENC  800
#define EDIM  256
#define GDIM  256
#define ADIM  128
#define IDIM  80
#define G3    768
#define NSL   16    // slices (blocks) per batch element
#define SLH   16    // GDIM/NSL h-elements per slice
#define SLT   50    // TENC/NSL encoder timesteps per slice

typedef unsigned short u16;
typedef unsigned int u32;

__device__ __forceinline__ float b2f(u16 u) {
  union { u32 i; float f; } x; x.i = ((u32)u) << 16; return x.f;
}
__device__ __forceinline__ u16 f2b(float f) {
  union { float f; u32 u; } x; x.f = f;
  u32 u = x.u; u += 0x7fffu + ((u >> 16) & 1u);
  return (u16)(u >> 16);
}
// 8 bf16 -> 8 f32 (16B load; works for global and LDS pointers after inlining)
__device__ __forceinline__ void ld8(const u16* p, float* w) {
  const uint4 q = *reinterpret_cast<const uint4*>(p);
  union { u32 i; float f; } c;
  c.i = q.x << 16;          w[0] = c.f;
  c.i = q.x & 0xffff0000u;  w[1] = c.f;
  c.i = q.y << 16;          w[2] = c.f;
  c.i = q.y & 0xffff0000u;  w[3] = c.f;
  c.i = q.z << 16;          w[4] = c.f;
  c.i = q.z & 0xffff0000u;  w[5] = c.f;
  c.i = q.w << 16;          w[6] = c.f;
  c.i = q.w & 0xffff0000u;  w[7] = c.f;
}
__device__ __forceinline__ void ldf8(const float* p, float* w) {
  const float4 a = *reinterpret_cast<const float4*>(p);
  const float4 b = *reinterpret_cast<const float4*>(p + 4);
  w[0] = a.x; w[1] = a.y; w[2] = a.z; w[3] = a.w;
  w[4] = b.x; w[5] = b.y; w[6] = b.z; w[7] = b.w;
}
__device__ __forceinline__ float fsigmoid(float x) {
  return __builtin_amdgcn_rcpf(1.f + __expf(-x));
}
__device__ __forceinline__ float ftanh(float x) {
  float e = __expf(2.f * x);
  return 1.f - 2.f * __builtin_amdgcn_rcpf(e + 1.f);
}
// Relaxed agent-scope atomics: sc0/sc1 bypass L1/L2 to LLC, no cache inv.
__device__ __forceinline__ void ast(float* p, float v) {
  __hip_atomic_store(p, v, __ATOMIC_RELAXED, __HIP_MEMORY_SCOPE_AGENT);
}
__device__ __forceinline__ float ald(const float* p) {
  return __hip_atomic_load(p, __ATOMIC_RELAXED, __HIP_MEMORY_SCOPE_AGENT);
}

// ---------------- K1: gi_x[b][t][g] = x_t . W_ih[:, :80] + b_ih (bf16 out) -----
__global__ __launch_bounds__(256) void k_gix(
    const float* __restrict__ gt, const float* __restrict__ W_ih,
    const float* __restrict__ b_ih, u16* __restrict__ gi_x) {
  __shared__ float sc_x[8][IDIM];
  const int tid = threadIdx.x;
  const int b = blockIdx.x / 50;
  const int t0 = (blockIdx.x % 50) * 8;
  for (int idx = tid; idx < 8 * IDIM; idx += 256) {
    int row = idx / IDIM, col = idx % IDIM;
    sc_x[row][col] = gt[((size_t)b * TDEC + t0 + row) * IDIM + col];
  }
  __syncthreads();
  for (int kk = 0; kk < 3; ++kk) {
    const int g = tid + 256 * kk;
    const float* wrow = W_ih + (size_t)g * 336;
    float acc[8] = {0,0,0,0,0,0,0,0};
    #pragma unroll 2
    for (int k8 = 0; k8 < IDIM / 8; ++k8) {
      float w[8]; ldf8(wrow + (k8 << 3), w);
      #pragma unroll
      for (int tt = 0; tt < 8; ++tt) {
        const float* x = &sc_x[tt][k8 << 3];
        acc[tt] += w[0]*x[0] + w[1]*x[1] + w[2]*x[2] + w[3]*x[3]
                 + w[4]*x[4] + w[5]*x[5] + w[6]*x[6] + w[7]*x[7];
      }
    }
    const float bias = b_ih[g];
    #pragma unroll
    for (int tt = 0; tt < 8; ++tt)
      gi_x[((size_t)b * TDEC + t0 + tt) * G3 + g] = f2b(acc[tt] + bias);
  }
}

// ------- K2: enc_proj (bf16) + bf16 copy of enc_feat ---------------------------
__global__ __launch_bounds__(256) void k_encp(
    const float* __restrict__ enc_feat, const float* __restrict__ W_enc,
    u16* __restrict__ encp, u16* __restrict__ enc_bf) {
  __shared__ float sc_x[16][EDIM];
  const int tid = threadIdx.x;
  const int b = blockIdx.x / 50;
  const int te0 = (blockIdx.x % 50) * 16;
  for (int idx = tid; idx < 16 * EDIM; idx += 256) {
    int row = idx >> 8, col = idx & 255;
    sc_x[row][col] = enc_feat[((size_t)b * TENC + te0 + row) * EDIM + col];
  }
  __syncthreads();
  const int a = tid & 127;
  const int tg = tid >> 7;
  const float* wrow = W_enc + (size_t)a * EDIM;
  float acc[8] = {0,0,0,0,0,0,0,0};
  #pragma unroll 4
  for (int k8 = 0; k8 < EDIM / 8; ++k8) {
    float w[8]; ldf8(wrow + (k8 << 3), w);
    #pragma unroll
    for (int tt = 0; tt < 8; ++tt) {
      const float* x = &sc_x[tg * 8 + tt][k8 << 3];
      acc[tt] += w[0]*x[0] + w[1]*x[1] + w[2]*x[2] + w[3]*x[3]
               + w[4]*x[4] + w[5]*x[5] + w[6]*x[6] + w[7]*x[7];
    }
  }
  #pragma unroll
  for (int tt = 0; tt < 8; ++tt)
    encp[((size_t)b * TENC + te0 + tg * 8 + tt) * ADIM + a] = f2b(acc[tt]);
  for (int idx = tid; idx < 16 * EDIM; idx += 256)
    enc_bf[((size_t)b * TENC + te0) * EDIM + idx] = f2b(sc_x[idx >> 8][idx & 255]);
}

// ---------------- K3: persistent step loop (16 blocks per batch elem) ----------
__global__ __launch_bounds__(256) void k_decode(
    const u16* __restrict__ enc_bf, const float* __restrict__ W_ih,
    const float* __restrict__ W_hh, const float* __restrict__ b_hh,
    const float* __restrict__ W_dec, const float* __restrict__ b_attn,
    const float* __restrict__ v_attn, const u16* __restrict__ gi_x,
    const u16* __restrict__ encp, float* __restrict__ stash,
    float* __restrict__ Xh, float* __restrict__ Xdec,
    float* __restrict__ Xctx, float* __restrict__ Xsum,
    int* __restrict__ flagA, int* __restrict__ flagB,
    float* __restrict__ out_attn) {
  // rows 0..47: W_ih ctx-cols (gate-major), rows 48..95: W_hh. 264 = 256+8 pad.
  __shared__ u16 sW[96 * 264];        // 50688 B
  __shared__ u16 sWd[128 * 24];       // 6144 B (row = 16 used + 8 pad)
  __shared__ float sc_in[512];        // [0..256)=ctx(t-1), [256..512)=h(t-1)
  __shared__ float sc_dec[ADIM];
  __shared__ float sc_g0[48];
  __shared__ float sc_g1[48];
  __shared__ float sc_hnl[SLH];
  __shared__ float sc_w[SLT];
  __shared__ float sc_v[ADIM];
  __shared__ float sc_ba[ADIM];
  __shared__ float sc_bhh[48];
  __shared__ float sc_xs[NSL];

  const int tid = threadIdx.x;
  const int b = blockIdx.x & 31;
  const int j = blockIdx.x >> 5;

  // ---- one-time staging: weights -> LDS bf16 ----
  for (int it = tid; it < 96 * 32; it += 256) {
    const int q = it >> 5, k0 = (it & 31) << 3;
    const float* src;
    if (q < 48) {
      const int gate = q >> 4, i = q & 15;
      src = W_ih + (size_t)(gate * 256 + SLH * j + i) * 336 + 80 + k0;
    } else {
      const int r = q - 48, gate = r >> 4, i = r & 15;
      src = W_hh + (size_t)(gate * 256 + SLH * j + i) * 256 + k0;
    }
    float w[8]; ldf8(src, w);
    uint4 pk;
    pk.x = (u32)f2b(w[0]) | ((u32)f2b(w[1]) << 16);
    pk.y = (u32)f2b(w[2]) | ((u32)f2b(w[3]) << 16);
    pk.z = (u32)f2b(w[4]) | ((u32)f2b(w[5]) << 16);
    pk.w = (u32)f2b(w[6]) | ((u32)f2b(w[7]) << 16);
    *reinterpret_cast<uint4*>(&sW[q * 264 + k0]) = pk;
  }
  for (int it = tid; it < 128 * 2; it += 256) {
    const int q = it >> 1, k0 = (it & 1) << 3;
    float w[8]; ldf8(W_dec + (size_t)q * GDIM + SLH * j + k0, w);
    uint4 pk;
    pk.x = (u32)f2b(w[0]) | ((u32)f2b(w[1]) << 16);
    pk.y = (u32)f2b(w[2]) | ((u32)f2b(w[3]) << 16);
    pk.z = (u32)f2b(w[4]) | ((u32)f2b(w[5]) << 16);
    pk.w = (u32)f2b(w[6]) | ((u32)f2b(w[7]) << 16);
    *reinterpret_cast<uint4*>(&sWd[q * 24 + k0]) = pk;
  }
  if (tid < ADIM) { sc_v[tid] = v_attn[tid]; sc_ba[tid] = b_attn[tid]; }
  if (tid < 48) {
    const int gate = tid >> 4, i = tid & 15;
    sc_bhh[tid] = b_hh[gate * 256 + SLH * j + i];
  }
  sc_in[tid] = 0.f;
  sc_in[256 + tid] = 0.f;
  __syncthreads();

  // per-thread phase-1 constants
  const int q1 = tid >> 1, h1 = tid & 1;            // q1: lds row, h1: k-half
  int grow1 = 0;
  if (q1 < 48) grow1 = (q1 >> 4) * 256 + SLH * j + (q1 & 15);

  for (int t = 0; t < TDEC; ++t) {
    // -------- phase 1: gate dots from LDS weights ----------------------------
    if (tid < 192) {
      const u16* wp = &sW[q1 * 264 + h1 * 128];
      const float* act = sc_in + ((q1 < 48) ? 0 : 256) + h1 * 128;
      float acc = 0.f;
      #pragma unroll 8
      for (int k8 = 0; k8 < 16; ++k8) {
        float w[8]; ld8(wp + (k8 << 3), w);
        const float* a8 = act + (k8 << 3);
        acc += w[0]*a8[0] + w[1]*a8[1] + w[2]*a8[2] + w[3]*a8[3]
             + w[4]*a8[4] + w[5]*a8[5] + w[6]*a8[6] + w[7]*a8[7];
      }
      acc += __shfl_xor(acc, 1);
      if (h1 == 0) {
        if (q1 < 48)
          sc_g0[q1] = acc + b2f(gi_x[((size_t)b * TDEC + t) * G3 + grow1]);
        else
          sc_g1[q1 - 48] = acc + sc_bhh[q1 - 48];
      }
    }
    __syncthreads();
    if (tid < SLH) {  // GRU pointwise; publish h slice
      const float gr = sc_g0[tid] + sc_g1[tid];
      const float gz = sc_g0[SLH + tid] + sc_g1[SLH + tid];
      const float rr = fsigmoid(gr);
      const float zz = fsigmoid(gz);
      const float nn = ftanh(sc_g0[2 * SLH + tid] + rr * sc_g1[2 * SLH + tid]);
      const float hp = sc_in[256 + SLH * j + tid];
      const float hn = (1.f - zz) * nn + zz * hp;
      sc_hnl[tid] = hn;
      ast(&Xh[b * GDIM + SLH * j + tid], hn);
      stash[((size_t)b * TDEC + t) * 512 + SLH * j + tid] = hn;
    }
    __syncthreads();
    if (tid < ADIM) {  // dec_proj partial from this block's h slice (LDS bf16)
      const u16* wp = &sWd[tid * 24];
      float acc = 0.f;
      #pragma unroll
      for (int k8 = 0; k8 < 2; ++k8) {
        float w[8]; ld8(wp + (k8 << 3), w);
        const float* a8 = sc_hnl + (k8 << 3);
        acc += w[0]*a8[0] + w[1]*a8[1] + w[2]*a8[2] + w[3]*a8[3]
             + w[4]*a8[4] + w[5]*a8[5] + w[6]*a8[6] + w[7]*a8[7];
      }
      ast(&Xdec[(b * NSL + j) * ADIM + tid], acc);
    }
    __syncthreads();  // drains vmcnt(0): Xh/Xdec committed to LLC
    if (tid == 0)
      __hip_atomic_store(&flagA[b * NSL + j], t + 1, __ATOMIC_RELAXED,
                         __HIP_MEMORY_SCOPE_AGENT);
    // -------- wait A ---------------------------------------------------------
    if (tid < NSL)
      while (__hip_atomic_load(&flagA[b * NSL + tid], __ATOMIC_RELAXED,
                               __HIP_MEMORY_SCOPE_AGENT) < t + 1) {}
    __syncthreads();
    sc_in[256 + tid] = ald(&Xh[b * GDIM + tid]);  // h(t) for next step
    if (tid < ADIM) {
      float d = sc_ba[tid];
      #pragma unroll
      for (int jj = 0; jj < NSL; ++jj) d += ald(&Xdec[(b * NSL + jj) * ADIM + tid]);
      sc_dec[tid] = d;
    }
    __syncthreads();
    // -------- phase 2a: scores for this block's 50 encoder steps -------------
    if (tid < 2 * SLT) {
      const int te = tid >> 1, half = tid & 1;
      const u16* ep = encp + ((size_t)b * TENC + SLT * j + te) * ADIM + 64 * half;
      const float* dptr = sc_dec + 64 * half;
      const float* vptr = sc_v + 64 * half;
      float s = 0.f;
      #pragma unroll 2
      for (int k8 = 0; k8 < 8; ++k8) {
        float w[8]; ld8(ep + (k8 << 3), w);
        #pragma unroll
        for (int i = 0; i < 8; ++i) {
          const int a = (k8 << 3) + i;
          s += ftanh(w[i] + dptr[a]) * vptr[a];
        }
      }
      s += __shfl_xor(s, 1);
      if (half == 0) sc_w[te] = __expf(s);  // |s| <= ||v||_1 ~ 5: max-free safe
    }
    __syncthreads();
    if (tid < 64) {  // partial exp-sum over this slice
      float v = (tid < SLT) ? sc_w[tid] : 0.f;
      #pragma unroll
      for (int off = 1; off < 64; off <<= 1) v += __shfl_xor(v, off);
      if (tid == 0) ast(&Xsum[b * NSL + j], v);
    }
    {  // phase 2b: unnormalized ctx partial (bf16 enc copy, coalesced columns)
      const u16* ef = enc_bf + ((size_t)b * TENC + SLT * j) * EDIM + tid;
      float pc = 0.f;
      #pragma unroll 5
      for (int te = 0; te < SLT; ++te)
        pc += sc_w[te] * b2f(ef[(size_t)te * EDIM]);
      ast(&Xctx[(b * NSL + j) * EDIM + tid], pc);
    }
    __syncthreads();  // drains vmcnt(0): Xsum/Xctx committed to LLC
    if (tid == 0)
      __hip_atomic_store(&flagB[b * NSL + j], t + 1, __ATOMIC_RELAXED,
                         __HIP_MEMORY_SCOPE_AGENT);
    // -------- wait B ---------------------------------------------------------
    if (tid < NSL) {
      while (__hip_atomic_load(&flagB[b * NSL + tid], __ATOMIC_RELAXED,
                               __HIP_MEMORY_SCOPE_AGENT) < t + 1) {}
      sc_xs[tid] = ald(&Xsum[b * NSL + tid]);
    }
    __syncthreads();
    {
      float S = 0.f;
      #pragma unroll
      for (int jj = 0; jj < NSL; ++jj) S += sc_xs[jj];
      float c = 0.f;
      #pragma unroll
      for (int jj = 0; jj < NSL; ++jj) c += ald(&Xctx[(b * NSL + jj) * EDIM + tid]);
      const float invS = __builtin_amdgcn_rcpf(S);
      const float cv = c * invS;
      sc_in[tid] = cv;  // ctx(t) for next step
      if (j == 0) stash[((size_t)b * TDEC + t) * 512 + EDIM + tid] = cv;
      if (tid < SLT)
        out_attn[((size_t)b * TDEC + t) * TENC + SLT * j + tid] =
            sc_w[tid] * invS;
    }
    __syncthreads();
  }
}

// ---------------- K4: pred = log_softmax([h;ctx] . W_out^T + b_out) ------------
__global__ __launch_bounds__(256) void k_pred(
    const float* __restrict__ stash, const float* __restrict__ W_out,
    const float* __restrict__ b_out, float* __restrict__ out_pred) {
  __shared__ float sc_s[4][512];
  __shared__ float sc_lp[2][4][IDIM];
  __shared__ float sc_l[4][IDIM];
  __shared__ float sc_lse[4];
  const int tid = threadIdx.x;
  const int b = blockIdx.x / 100;
  const int t0 = (blockIdx.x % 100) * 4;
  for (int idx = tid; idx < 4 * 512; idx += 256)
    sc_s[idx >> 9][idx & 511] = stash[((size_t)b * TDEC + t0) * 512 + idx];
  __syncthreads();
  const int o = tid & 127, kh = tid >> 7;
  if (o < IDIM) {
    const float* wrow = W_out + (size_t)o * 512 + kh * 256;
    float acc[4] = {0,0,0,0};
    #pragma unroll 4
    for (int k8 = 0; k8 < 32; ++k8) {
      float w[8]; ldf8(wrow + (k8 << 3), w);
      #pragma unroll
      for (int tt = 0; tt < 4; ++tt) {
        const float* x = &sc_s[tt][kh * 256 + (k8 << 3)];
        acc[tt] += w[0]*x[0] + w[1]*x[1] + w[2]*x[2] + w[3]*x[3]
                 + w[4]*x[4] + w[5]*x[5] + w[6]*x[6] + w[7]*x[7];
      }
    }
    #pragma unroll
    for (int tt = 0; tt < 4; ++tt) sc_lp[kh][tt][o] = acc[tt];
  }
  __syncthreads();
  if (tid < IDIM) {
    const float bb = b_out[tid];
    #pragma unroll
    for (int tt = 0; tt < 4; ++tt)
      sc_l[tt][tid] = sc_lp[0][tt][tid] + sc_lp[1][tt][tid] + bb;
  }
  __syncthreads();
  {
    const int w = tid >> 6, lane = tid & 63;
    const float a0 = sc_l[w][lane];
    const float a1 = (lane < IDIM - 64) ? sc_l[w][lane + 64] : -1e30f;
    float m = fmaxf(a0, a1);
    #pragma unroll
    for (int off = 1; off < 64; off <<= 1) m = fmaxf(m, __shfl_xor(m, off));
    float e = __expf(a0 - m) + ((lane < IDIM - 64) ? __expf(a1 - m) : 0.f);
    #pragma unroll
    for (int off = 1; off < 64; off <<= 1) e += __shfl_xor(e, off);
    if (lane == 0) sc_lse[w] = m + __logf(e);
  }
  __syncthreads();
  for (int idx = tid; idx < 4 * IDIM; idx += 256) {
    const int tt = idx / IDIM, oo = idx % IDIM;
    out_pred[((size_t)b * TDEC + t0 + tt) * IDIM + oo] =
        sc_l[tt][oo] - sc_lse[tt];
  }
}

extern "C" void kernel_launch(void* const* d_in, const int* in_sizes, int n_in,
                              void* d_out, int out_size, void* d_ws, size_t ws_size,
                              hipStream_t stream) {
  const float* enc_feat = (const float*)d_in[0];
  const float* gt       = (const float*)d_in[1];
  const float* W_ih     = (const float*)d_in[2];
  const float* W_hh     = (const float*)d_in[3];
  const float* b_ih     = (const float*)d_in[4];
  const float* b_hh     = (const float*)d_in[5];
  const float* W_enc    = (const float*)d_in[6];
  const float* W_dec    = (const float*)d_in[7];
  const float* b_attn   = (const float*)d_in[8];
  const float* v_attn   = (const float*)d_in[9];
  const float* W_out    = (const float*)d_in[10];
  const float* b_out    = (const float*)d_in[11];
  float* out_pred = (float*)d_out;
  float* out_attn = out_pred + (size_t)BB * TDEC * IDIM;

  char* ws = (char*)d_ws;
  size_t off = 0;
  u16* gi_x   = (u16*)(ws + off);   off += (size_t)BB * TDEC * G3 * 2;
  u16* encp   = (u16*)(ws + off);   off += (size_t)BB * TENC * ADIM * 2;
  u16* enc_bf = (u16*)(ws + off);   off += (size_t)BB * TENC * EDIM * 2;
  float* stash= (float*)(ws + off); off += (size_t)BB * TDEC * 512 * 4;
  float* Xh   = (float*)(ws + off); off += (size_t)BB * GDIM * 4;
  float* Xdec = (float*)(ws + off); off += (size_t)BB * NSL * ADIM * 4;
  float* Xctx = (float*)(ws + off); off += (size_t)BB * NSL * EDIM * 4;
  float* Xsum = (float*)(ws + off); off += (size_t)BB * NSL * 4;
  int* flagA  = (int*)(ws + off);   off += (size_t)BB * NSL * 4;
  int* flagB  = (int*)(ws + off);   off += (size_t)BB * NSL * 4;

  hipMemsetAsync(flagA, 0, (size_t)BB * NSL * 4 * 2, stream);  // zero A+B

  hipLaunchKernelGGL(k_gix, dim3(BB * 50), dim3(256), 0, stream,
                     gt, W_ih, b_ih, gi_x);
  hipLaunchKernelGGL(k_encp, dim3(BB * 50), dim3(256), 0, stream,
                     enc_feat, W_enc, encp, enc_bf);
  hipLaunchKernelGGL(k_decode, dim3(BB * NSL), dim3(256), 0, stream,
                     enc_bf, W_ih, W_hh, b_hh, W_dec, b_attn, v_attn,
                     gi_x, encp, stash, Xh, Xdec, Xctx, Xsum,
                     flagA, flagB, out_attn);
  hipLaunchKernelGGL(k_pred, dim3(BB * 100), dim3(256), 0, stream,
                     stash, W_out, b_out, out_pred);
}